// Round 1
// baseline (717.578 us; speedup 1.0000x reference)
//
#include <hip/hip_runtime.h>
#include <cstdint>
#include <cstddef>

#define NOBJ 32
#define NP   992
#define DD   256
#define SP   196   // 14*14
#define OC   151
#define RC   51
#define RED  64
#define KIN  4251  // 4096 + 151 + 4

// ws layout (float offsets)
#define OFF_PART   0u        // 64*32*256 = 524288
#define OFF_OBJF   524288u   // 8192
#define OFF_SS     532480u   // 253952
#define OFF_SO     786432u   // 253952
#define OFF_SB     1040384u  // 253952
#define OFF_GATED  1294336u  // 992*768 = 761856
#define OFF_RELF   2056192u  // 253952
#define OFF_H      2310144u  // 262144
// total 2572288 floats = ~10.3 MB

// ---------------- K1: split-K partial of obj_in @ W_emb1 -------------------
__global__ void k_emb1_partial(const float* __restrict__ roi,
                               const float* __restrict__ logits,
                               const float* __restrict__ bbox,
                               const float* __restrict__ W1,
                               float* __restrict__ part) {
  const int chunk = blockIdx.x;   // 64 chunks of 67 k's
  const int t = threadIdx.x;      // output column
  int k0 = chunk * 67;
  int k1 = k0 + 67; if (k1 > KIN) k1 = KIN;
  float acc[NOBJ];
#pragma unroll
  for (int i = 0; i < NOBJ; ++i) acc[i] = 0.f;
  for (int k = k0; k < k1; ++k) {
    float w = W1[(size_t)k * DD + t];
    const float* xp; int stride;
    if (k < 4096)            { xp = roi    + k;              stride = 4096; }
    else if (k < 4096 + OC)  { xp = logits + (k - 4096);     stride = OC;   }
    else                     { xp = bbox   + (k - 4096 - OC); stride = 4;   }
#pragma unroll
    for (int i = 0; i < NOBJ; ++i) { acc[i] += xp[0] * w; xp += stride; }
  }
  float* pout = part + (size_t)chunk * (NOBJ * DD) + t;
#pragma unroll
  for (int i = 0; i < NOBJ; ++i) pout[i * DD] = acc[i];
}

// ---------------- K2: reduce partials, relu, @ W_emb2 ----------------------
__global__ void k_emb2(const float* __restrict__ part,
                       const float* __restrict__ b1,
                       const float* __restrict__ W2,
                       const float* __restrict__ b2,
                       float* __restrict__ objf) {
  const int i = blockIdx.x, t = threadIdx.x;
  __shared__ __align__(16) float h[DD];
  float a0 = 0, a1 = 0, a2 = 0, a3 = 0;
  for (int c = 0; c < 64; c += 4) {
    a0 += part[(size_t)(c + 0) * (NOBJ * DD) + i * DD + t];
    a1 += part[(size_t)(c + 1) * (NOBJ * DD) + i * DD + t];
    a2 += part[(size_t)(c + 2) * (NOBJ * DD) + i * DD + t];
    a3 += part[(size_t)(c + 3) * (NOBJ * DD) + i * DD + t];
  }
  h[t] = fmaxf((a0 + a1) + (a2 + a3) + b1[t], 0.f);
  __syncthreads();
  float s0 = 0, s1 = 0, s2 = 0, s3 = 0;
  for (int k = 0; k < DD; k += 4) {
    float4 hh = *(const float4*)&h[k];
    s0 += hh.x * W2[(k + 0) * DD + t];
    s1 += hh.y * W2[(k + 1) * DD + t];
    s2 += hh.z * W2[(k + 2) * DD + t];
    s3 += hh.w * W2[(k + 3) * DD + t];
  }
  objf[i * DD + t] = (s0 + s1) + (s2 + s3) + b2[t];
}

// ---------------- K3: one pass over union_features, 3 masked means ---------
__global__ void k_union(const float* __restrict__ uf,
                        const float* __restrict__ bbox,
                        const int* __restrict__ pairs,
                        float* __restrict__ ss, float* __restrict__ so,
                        float* __restrict__ sbg) {
  const int p = blockIdx.x, t = threadIdx.x;   // t = channel d
  __shared__ __align__(16) float wS[SP];
  __shared__ __align__(16) float wO[SP];
  __shared__ __align__(16) float wB[SP];
  if (t < SP) {
    int si = pairs[2 * p], oi = pairs[2 * p + 1];
    float sx1 = bbox[si * 4 + 0], sy1 = bbox[si * 4 + 1];
    float sx2 = bbox[si * 4 + 2], sy2 = bbox[si * 4 + 3];
    float ox1 = bbox[oi * 4 + 0], oy1 = bbox[oi * 4 + 1];
    float ox2 = bbox[oi * 4 + 2], oy2 = bbox[oi * 4 + 3];
    float ux = fminf(sx1, ox1), uy = fminf(sy1, oy1);
    float xr = 14.f / fmaxf(sx2 - ux, ox2 - ux);
    float yr = 14.f / fmaxf(sy2 - uy, oy2 - uy);
    float xs0 = rintf((sx1 - ux) * xr), xs1 = rintf((sx2 - ux) * xr);
    float xo0 = rintf((ox1 - ux) * xr), xo1 = rintf((ox2 - ux) * xr);
    float ys0 = rintf((sy1 - uy) * yr), ys1 = rintf((sy2 - uy) * yr);
    float yo0 = rintf((oy1 - uy) * yr), yo1 = rintf((oy2 - uy) * yr);
    int a = t / 14, b = t - a * 14;
    float fa = (float)a, fb = (float)b;
    float sm = (fa >= xs0 && fa < xs1 && fb >= ys0 && fb < ys1) ? 1.f : 0.f;
    float om = (fa >= xo0 && fa < xo1 && fb >= yo0 && fb < yo1) ? 1.f : 0.f;
    float bm = fminf(fmaxf(1.f - sm - om, 0.f), 1.f);
    wS[t] = sm; wO[t] = om; wB[t] = bm;
  }
  __syncthreads();
  const float4* u4 = (const float4*)(uf + ((size_t)p * DD + t) * SP);
  float as0 = 0, as1 = 0, ao0 = 0, ao1 = 0, ab0 = 0, ab1 = 0;
#pragma unroll 7
  for (int j = 0; j < SP / 4; ++j) {
    float4 v  = u4[j];
    float4 ms = *(const float4*)&wS[4 * j];
    float4 mo = *(const float4*)&wO[4 * j];
    float4 mb = *(const float4*)&wB[4 * j];
    as0 += v.x * ms.x + v.y * ms.y;  as1 += v.z * ms.z + v.w * ms.w;
    ao0 += v.x * mo.x + v.y * mo.y;  ao1 += v.z * mo.z + v.w * mo.w;
    ab0 += v.x * mb.x + v.y * mb.y;  ab1 += v.z * mb.z + v.w * mb.w;
  }
  const float inv = 1.f / 196.f;
  ss [(size_t)p * DD + t] = (as0 + as1) * inv;
  so [(size_t)p * DD + t] = (ao0 + ao1) * inv;
  sbg[(size_t)p * DD + t] = (ab0 + ab1) * inv;
}

// ---------------- K4a: attention gates (4 pairs / block) -------------------
__global__ void k_att(const float* __restrict__ ss, const float* __restrict__ so,
                      const float* __restrict__ sb,
                      const float* __restrict__ fc1w, const float* __restrict__ fc1b,
                      const float* __restrict__ fc2w, const float* __restrict__ fc2b,
                      float* __restrict__ gated) {
  const int p0 = blockIdx.x * 4;
  const int t = threadIdx.x;
  __shared__ __align__(16) float sg[4][768];
  __shared__ __align__(16) float ha[4][192];
  for (int idx = t; idx < 4 * 768; idx += 256) {
    int r = idx / 768, c = idx - r * 768;
    int br = c >> 8, ch = c & 255;
    const float* sp = (br == 0) ? ss : (br == 1) ? so : sb;
    sg[r][c] = sp[(size_t)(p0 + r) * DD + ch];
  }
  __syncthreads();
  if (t < 192) {
    const int br = t >> 6, c = t & 63;
    float acc0 = 0, acc1 = 0, acc2 = 0, acc3 = 0;
    const float* w = fc1w + br * (DD * RED) + c;
    const int sbase = br * DD;
    for (int k = 0; k < DD; k += 4) {
      float w0 = w[(k + 0) * RED], w1 = w[(k + 1) * RED];
      float w2 = w[(k + 2) * RED], w3 = w[(k + 3) * RED];
      float4 sA = *(const float4*)&sg[0][sbase + k];
      float4 sB = *(const float4*)&sg[1][sbase + k];
      float4 sC = *(const float4*)&sg[2][sbase + k];
      float4 sD = *(const float4*)&sg[3][sbase + k];
      acc0 += sA.x * w0 + sA.y * w1 + sA.z * w2 + sA.w * w3;
      acc1 += sB.x * w0 + sB.y * w1 + sB.z * w2 + sB.w * w3;
      acc2 += sC.x * w0 + sC.y * w1 + sC.z * w2 + sC.w * w3;
      acc3 += sD.x * w0 + sD.y * w1 + sD.z * w2 + sD.w * w3;
    }
    float bb = fc1b[br * RED + c];
    ha[0][t] = fmaxf(acc0 + bb, 0.f);
    ha[1][t] = fmaxf(acc1 + bb, 0.f);
    ha[2][t] = fmaxf(acc2 + bb, 0.f);
    ha[3][t] = fmaxf(acc3 + bb, 0.f);
  }
  __syncthreads();
  for (int br = 0; br < 3; ++br) {
    float acc0 = 0, acc1 = 0, acc2 = 0, acc3 = 0;
    const float* w = fc2w + br * (RED * DD) + t;
    const int hbase = br * RED;
    for (int k = 0; k < RED; k += 4) {
      float w0 = w[(k + 0) * DD], w1 = w[(k + 1) * DD];
      float w2 = w[(k + 2) * DD], w3 = w[(k + 3) * DD];
      float4 hA = *(const float4*)&ha[0][hbase + k];
      float4 hB = *(const float4*)&ha[1][hbase + k];
      float4 hC = *(const float4*)&ha[2][hbase + k];
      float4 hD = *(const float4*)&ha[3][hbase + k];
      acc0 += hA.x * w0 + hA.y * w1 + hA.z * w2 + hA.w * w3;
      acc1 += hB.x * w0 + hB.y * w1 + hB.z * w2 + hB.w * w3;
      acc2 += hC.x * w0 + hC.y * w1 + hC.z * w2 + hC.w * w3;
      acc3 += hD.x * w0 + hD.y * w1 + hD.z * w2 + hD.w * w3;
    }
    float bb = fc2b[br * DD + t];
    int cidx = br * DD + t;
    float g0 = 1.f / (1.f + expf(-(acc0 + bb)));
    float g1 = 1.f / (1.f + expf(-(acc1 + bb)));
    float g2 = 1.f / (1.f + expf(-(acc2 + bb)));
    float g3 = 1.f / (1.f + expf(-(acc3 + bb)));
    gated[(size_t)(p0 + 0) * 768 + cidx] = sg[0][cidx] * g0;
    gated[(size_t)(p0 + 1) * 768 + cidx] = sg[1][cidx] * g1;
    gated[(size_t)(p0 + 2) * 768 + cidx] = sg[2][cidx] * g2;
    gated[(size_t)(p0 + 3) * 768 + cidx] = sg[3][cidx] * g3;
  }
}

// ---------------- K4b: rel MLP (768->256 relu ->256), 4 pairs / block ------
__global__ void k_relmlp(const float* __restrict__ gated,
                         const float* __restrict__ Wc1, const float* __restrict__ bc1,
                         const float* __restrict__ Wc2, const float* __restrict__ bc2,
                         float* __restrict__ relf) {
  const int r0 = blockIdx.x * 4;
  const int t = threadIdx.x;
  __shared__ __align__(16) float g[4][768];
  __shared__ __align__(16) float h2[4][256];
  for (int idx = t; idx < 4 * 768; idx += 256) {
    int r = idx / 768, c = idx - r * 768;
    g[r][c] = gated[(size_t)(r0 + r) * 768 + c];
  }
  __syncthreads();
  {
    float a0 = 0, a1 = 0, a2 = 0, a3 = 0;
    const float* w = Wc1 + t;
    for (int k = 0; k < 768; k += 4) {
      float w0 = w[(k + 0) * DD], w1 = w[(k + 1) * DD];
      float w2 = w[(k + 2) * DD], w3 = w[(k + 3) * DD];
      float4 gA = *(const float4*)&g[0][k];
      float4 gB = *(const float4*)&g[1][k];
      float4 gC = *(const float4*)&g[2][k];
      float4 gD = *(const float4*)&g[3][k];
      a0 += gA.x * w0 + gA.y * w1 + gA.z * w2 + gA.w * w3;
      a1 += gB.x * w0 + gB.y * w1 + gB.z * w2 + gB.w * w3;
      a2 += gC.x * w0 + gC.y * w1 + gC.z * w2 + gC.w * w3;
      a3 += gD.x * w0 + gD.y * w1 + gD.z * w2 + gD.w * w3;
    }
    float bb = bc1[t];
    h2[0][t] = fmaxf(a0 + bb, 0.f);
    h2[1][t] = fmaxf(a1 + bb, 0.f);
    h2[2][t] = fmaxf(a2 + bb, 0.f);
    h2[3][t] = fmaxf(a3 + bb, 0.f);
  }
  __syncthreads();
  {
    float a0 = 0, a1 = 0, a2 = 0, a3 = 0;
    const float* w = Wc2 + t;
    for (int k = 0; k < DD; k += 4) {
      float w0 = w[(k + 0) * DD], w1 = w[(k + 1) * DD];
      float w2 = w[(k + 2) * DD], w3 = w[(k + 3) * DD];
      float4 hA = *(const float4*)&h2[0][k];
      float4 hB = *(const float4*)&h2[1][k];
      float4 hC = *(const float4*)&h2[2][k];
      float4 hD = *(const float4*)&h2[3][k];
      a0 += hA.x * w0 + hA.y * w1 + hA.z * w2 + hA.w * w3;
      a1 += hB.x * w0 + hB.y * w1 + hB.z * w2 + hB.w * w3;
      a2 += hC.x * w0 + hC.y * w1 + hC.z * w2 + hC.w * w3;
      a3 += hD.x * w0 + hD.y * w1 + hD.z * w2 + hD.w * w3;
    }
    float bb = bc2[t];
    relf[(size_t)(r0 + 0) * DD + t] = a0 + bb;
    relf[(size_t)(r0 + 1) * DD + t] = a1 + bb;
    relf[(size_t)(r0 + 2) * DD + t] = a2 + bb;
    relf[(size_t)(r0 + 3) * DD + t] = a3 + bb;
  }
}

// ---------------- K5: H = concat(objf, relf) @ W_gcn -----------------------
__global__ void k_gcn_h(const float* __restrict__ objf, const float* __restrict__ relf,
                        const float* __restrict__ Wg, float* __restrict__ H) {
  const int r0 = blockIdx.x * 4;   // 256 blocks
  const int t = threadIdx.x;
  __shared__ __align__(16) float fin[4][DD];
  for (int idx = t; idx < 4 * DD; idx += 256) {
    int r = idx >> 8, c = idx & 255;
    int row = r0 + r;
    fin[r][c] = (row < NOBJ) ? objf[row * DD + c]
                             : relf[(size_t)(row - NOBJ) * DD + c];
  }
  __syncthreads();
  float a0 = 0, a1 = 0, a2 = 0, a3 = 0;
  const float* w = Wg + t;
  for (int k = 0; k < DD; k += 4) {
    float w0 = w[(k + 0) * DD], w1 = w[(k + 1) * DD];
    float w2 = w[(k + 2) * DD], w3 = w[(k + 3) * DD];
    float4 fA = *(const float4*)&fin[0][k];
    float4 fB = *(const float4*)&fin[1][k];
    float4 fC = *(const float4*)&fin[2][k];
    float4 fD = *(const float4*)&fin[3][k];
    a0 += fA.x * w0 + fA.y * w1 + fA.z * w2 + fA.w * w3;
    a1 += fB.x * w0 + fB.y * w1 + fB.z * w2 + fB.w * w3;
    a2 += fC.x * w0 + fC.y * w1 + fC.z * w2 + fC.w * w3;
    a3 += fD.x * w0 + fD.y * w1 + fD.z * w2 + fD.w * w3;
  }
  H[(size_t)(r0 + 0) * DD + t] = a0;
  H[(size_t)(r0 + 1) * DD + t] = a1;
  H[(size_t)(r0 + 2) * DD + t] = a2;
  H[(size_t)(r0 + 3) * DD + t] = a3;
}

// ---------------- K6: object GCN rows + obj head ---------------------------
__global__ void k_obj_out(const float* __restrict__ H, const float* __restrict__ objf,
                          const int* __restrict__ pairs, const float* __restrict__ bg,
                          const float* __restrict__ Wop, const float* __restrict__ bop,
                          float* __restrict__ out) {
  const int i = blockIdx.x, t = threadIdx.x;
  __shared__ __align__(16) float gr[DD];
  float acc = 0.f;
  for (int j = 0; j < NOBJ; ++j) acc += H[j * DD + t];       // sum over all objects
  const int2* pr2 = (const int2*)pairs;
  for (int r = 0; r < NP; ++r) {
    int2 pr = pr2[r];
    if (pr.x == i || pr.y == i) acc += H[(size_t)(NOBJ + r) * DD + t];
  }
  float pre = acc * (1.f / 94.f);
  gr[t] = fmaxf(pre + bg[t], 0.f) + objf[i * DD + t];
  __syncthreads();
  if (t < OC) {
    float a0 = 0, a1 = 0, a2 = 0, a3 = 0;
    for (int k = 0; k < DD; k += 4) {
      float4 gg = *(const float4*)&gr[k];
      a0 += gg.x * Wop[(k + 0) * OC + t];
      a1 += gg.y * Wop[(k + 1) * OC + t];
      a2 += gg.z * Wop[(k + 2) * OC + t];
      a3 += gg.w * Wop[(k + 3) * OC + t];
    }
    out[i * OC + t] = (a0 + a1) + (a2 + a3) + bop[t];
  }
}

// ---------------- K7: rel GCN rows + rel head ------------------------------
__global__ void k_rel_out(const float* __restrict__ H, const float* __restrict__ relf,
                          const int* __restrict__ pairs, const float* __restrict__ bg,
                          const float* __restrict__ Wrp, const float* __restrict__ brp,
                          float* __restrict__ out) {
  const int r = blockIdx.x, t = threadIdx.x;
  __shared__ __align__(16) float gr[DD];
  __shared__ float red[4][64];
  int si = pairs[2 * r], oi = pairs[2 * r + 1];
  float hsum = H[si * DD + t] + H[oi * DD + t] + H[(size_t)(NOBJ + r) * DD + t];
  gr[t] = fmaxf(hsum * (1.f / 3.f) + bg[t], 0.f) + relf[(size_t)r * DD + t];
  __syncthreads();
  int q = t >> 6, c = t & 63;
  float a = 0.f;
  if (c < RC) {
    const float* w = Wrp + c;
    int k0 = q * 64;
    float a0 = 0, a1 = 0, a2 = 0, a3 = 0;
    for (int k = k0; k < k0 + 64; k += 4) {
      float4 gg = *(const float4*)&gr[k];
      a0 += gg.x * w[(k + 0) * RC];
      a1 += gg.y * w[(k + 1) * RC];
      a2 += gg.z * w[(k + 2) * RC];
      a3 += gg.w * w[(k + 3) * RC];
    }
    a = (a0 + a1) + (a2 + a3);
  }
  red[q][c] = a;
  __syncthreads();
  if (t < RC) {
    out[NOBJ * OC + (size_t)r * RC + t] =
        red[0][t] + red[1][t] + red[2][t] + red[3][t] + brp[t];
  }
}

extern "C" void kernel_launch(void* const* d_in, const int* in_sizes, int n_in,
                              void* d_out, int out_size, void* d_ws, size_t ws_size,
                              hipStream_t stream) {
  const float* roi   = (const float*)d_in[0];
  const float* bbox  = (const float*)d_in[1];
  const float* logit = (const float*)d_in[2];
  const float* uf    = (const float*)d_in[3];
  const int*   pairs = (const int*)d_in[4];
  const float* W1    = (const float*)d_in[5];
  const float* b1    = (const float*)d_in[6];
  const float* W2    = (const float*)d_in[7];
  const float* b2    = (const float*)d_in[8];
  const float* fc1w  = (const float*)d_in[9];
  const float* fc1b  = (const float*)d_in[10];
  const float* fc2w  = (const float*)d_in[11];
  const float* fc2b  = (const float*)d_in[12];
  const float* Wc1   = (const float*)d_in[13];
  const float* bc1   = (const float*)d_in[14];
  const float* Wc2   = (const float*)d_in[15];
  const float* bc2   = (const float*)d_in[16];
  const float* Wg    = (const float*)d_in[17];
  const float* bg    = (const float*)d_in[18];
  const float* Wop   = (const float*)d_in[19];
  const float* bop   = (const float*)d_in[20];
  const float* Wrp   = (const float*)d_in[21];
  const float* brp   = (const float*)d_in[22];

  float* ws    = (float*)d_ws;
  float* part  = ws + OFF_PART;
  float* objf  = ws + OFF_OBJF;
  float* ssb   = ws + OFF_SS;
  float* sob   = ws + OFF_SO;
  float* sbb   = ws + OFF_SB;
  float* gated = ws + OFF_GATED;
  float* relf  = ws + OFF_RELF;
  float* Hbuf  = ws + OFF_H;
  float* out   = (float*)d_out;

  k_emb1_partial<<<64, 256, 0, stream>>>(roi, logit, bbox, W1, part);
  k_emb2<<<NOBJ, 256, 0, stream>>>(part, b1, W2, b2, objf);
  k_union<<<NP, 256, 0, stream>>>(uf, bbox, pairs, ssb, sob, sbb);
  k_att<<<NP / 4, 256, 0, stream>>>(ssb, sob, sbb, fc1w, fc1b, fc2w, fc2b, gated);
  k_relmlp<<<NP / 4, 256, 0, stream>>>(gated, Wc1, bc1, Wc2, bc2, relf);
  k_gcn_h<<<(NOBJ + NP) / 4, 256, 0, stream>>>(objf, relf, Wg, Hbuf);
  k_obj_out<<<NOBJ, 256, 0, stream>>>(Hbuf, objf, pairs, bg, Wop, bop, out);
  k_rel_out<<<NP, 256, 0, stream>>>(Hbuf, relf, pairs, bg, Wrp, brp, out);
}

// Round 2
// 541.509 us; speedup vs baseline: 1.3251x; 1.3251x over previous
//
#include <hip/hip_runtime.h>
#include <cstdint>
#include <cstddef>

#define NOBJ 32
#define NP   992
#define DD   256
#define SP   196   // 14*14
#define OC   151
#define RC   51
#define RED  64
#define KIN  4251  // 4096 + 151 + 4
#define CH   128   // emb1 k-chunks
#define KPC  34    // ceil(4251/128)

// ---- ws layout (float offsets) ----
#define OFF_PART   0u         // 128*32*256 = 1048576
#define OFF_OBJF   1048576u   // 8192
#define OFF_SALL   1056768u   // 992*768 = 761856
#define OFF_RELF   1818624u   // 253952
#define OFF_H      2072576u   // 262144
#define OFF_W2T    2334720u   // 65536
#define OFF_WC1T   2400256u   // 196608
#define OFF_WC2T   2596864u   // 65536
#define OFF_WGT    2662400u   // 65536
#define OFF_FC1WT  2727936u   // 49152
#define OFF_FC2WT  2777088u   // 49152
#define OFF_WOPT   2826240u   // 38656
#define OFF_WRPT   2864896u   // 13056
// total 2877952 floats = 11.5 MB

// ============ T: transpose all weight matrices (coalesced read) ============
__global__ void k_transpose(const float* __restrict__ W2,  const float* __restrict__ Wc1,
                            const float* __restrict__ Wc2, const float* __restrict__ Wg,
                            const float* __restrict__ f1w, const float* __restrict__ f2w,
                            const float* __restrict__ Wop, const float* __restrict__ Wrp,
                            float* __restrict__ W2T,  float* __restrict__ Wc1T,
                            float* __restrict__ Wc2T, float* __restrict__ WgT,
                            float* __restrict__ f1wT, float* __restrict__ f2wT,
                            float* __restrict__ WopT, float* __restrict__ WrpT) {
  const int b = blockIdx.x, t = threadIdx.x;
  if (b < 256) {                     // W2 256x256
    int idx = b * 256 + t; int k = idx >> 8, c = idx & 255;
    W2T[c * 256 + k] = W2[idx];
  } else if (b < 1024) {             // Wc1 768x256
    int idx = (b - 256) * 256 + t; int k = idx >> 8, c = idx & 255;
    Wc1T[c * 768 + k] = Wc1[idx];
  } else if (b < 1280) {             // Wc2 256x256
    int idx = (b - 1024) * 256 + t; int k = idx >> 8, c = idx & 255;
    Wc2T[c * 256 + k] = Wc2[idx];
  } else if (b < 1536) {             // Wg 256x256
    int idx = (b - 1280) * 256 + t; int k = idx >> 8, c = idx & 255;
    WgT[c * 256 + k] = Wg[idx];
  } else if (b < 1728) {             // fc1w 3 x 256x64
    int idx = (b - 1536) * 256 + t; int br = idx >> 14; int rem = idx & 16383;
    int k = rem >> 6, c = rem & 63;
    f1wT[br * 16384 + c * 256 + k] = f1w[idx];
  } else if (b < 1920) {             // fc2w 3 x 64x256
    int idx = (b - 1728) * 256 + t; int br = idx >> 14; int rem = idx & 16383;
    int k = rem >> 8, c = rem & 255;
    f2wT[br * 16384 + c * 64 + k] = f2w[idx];
  } else if (b < 2071) {             // Wop 256x151
    int idx = (b - 1920) * 256 + t; int k = idx / OC, c = idx - k * OC;
    WopT[c * 256 + k] = Wop[idx];
  } else {                           // Wrp 256x51
    int idx = (b - 2071) * 256 + t; int k = idx / RC, c = idx - k * RC;
    WrpT[c * 256 + k] = Wrp[idx];
  }
}

// ============ K1: split-K partial of obj_in @ W_emb1 (128 chunks) ==========
__global__ void k_emb1_partial(const float* __restrict__ roi,
                               const float* __restrict__ logits,
                               const float* __restrict__ bbox,
                               const float* __restrict__ W1,
                               float* __restrict__ part) {
  const int chunk = blockIdx.x;
  const int t = threadIdx.x;
  int k0 = chunk * KPC;
  int k1 = k0 + KPC; if (k1 > KIN) k1 = KIN;
  float acc[NOBJ];
#pragma unroll
  for (int i = 0; i < NOBJ; ++i) acc[i] = 0.f;
#pragma unroll 2
  for (int k = k0; k < k1; ++k) {
    float w = W1[(size_t)k * DD + t];
    const float* xp; int stride;
    if (k < 4096)            { xp = roi    + k;               stride = 4096; }
    else if (k < 4096 + OC)  { xp = logits + (k - 4096);      stride = OC;   }
    else                     { xp = bbox   + (k - 4096 - OC); stride = 4;    }
#pragma unroll
    for (int i = 0; i < NOBJ; ++i) { acc[i] += xp[0] * w; xp += stride; }
  }
  float* pout = part + (size_t)chunk * (NOBJ * DD) + t;
#pragma unroll
  for (int i = 0; i < NOBJ; ++i) pout[i * DD] = acc[i];
}

// ============ K2: reduce partials, relu, @ W2T =============================
__global__ void k_emb2(const float* __restrict__ part,
                       const float* __restrict__ b1,
                       const float* __restrict__ W2T,
                       const float* __restrict__ b2,
                       float* __restrict__ objf) {
  const int i = blockIdx.x, t = threadIdx.x;
  __shared__ __align__(16) float h[DD];
  float s[8];
#pragma unroll
  for (int u = 0; u < 8; ++u) s[u] = 0.f;
#pragma unroll
  for (int c0 = 0; c0 < CH; c0 += 8) {
#pragma unroll
    for (int u = 0; u < 8; ++u)
      s[u] += part[(size_t)(c0 + u) * (NOBJ * DD) + i * DD + t];
  }
  float tot = ((s[0] + s[1]) + (s[2] + s[3])) + ((s[4] + s[5]) + (s[6] + s[7]));
  h[t] = fmaxf(tot + b1[t], 0.f);
  __syncthreads();
  const float4* w4 = (const float4*)(W2T + (size_t)t * DD);
  float a0 = 0, a1 = 0, a2 = 0, a3 = 0;
#pragma unroll 8
  for (int j = 0; j < DD / 4; ++j) {
    float4 wv = w4[j];
    float4 hv = *(const float4*)&h[4 * j];
    a0 += hv.x * wv.x; a1 += hv.y * wv.y; a2 += hv.z * wv.z; a3 += hv.w * wv.w;
  }
  objf[i * DD + t] = (a0 + a1) + (a2 + a3) + b2[t];
}

// ============ K3: one pass over union_features, 3 masked means =============
__global__ void k_union(const float* __restrict__ uf,
                        const float* __restrict__ bbox,
                        const int* __restrict__ pairs,
                        float* __restrict__ sAll) {
  const int p = blockIdx.x, t = threadIdx.x;
  __shared__ __align__(16) float wS[SP];
  __shared__ __align__(16) float wO[SP];
  __shared__ __align__(16) float wB[SP];
  if (t < SP) {
    int si = pairs[2 * p], oi = pairs[2 * p + 1];
    float sx1 = bbox[si * 4 + 0], sy1 = bbox[si * 4 + 1];
    float sx2 = bbox[si * 4 + 2], sy2 = bbox[si * 4 + 3];
    float ox1 = bbox[oi * 4 + 0], oy1 = bbox[oi * 4 + 1];
    float ox2 = bbox[oi * 4 + 2], oy2 = bbox[oi * 4 + 3];
    float ux = fminf(sx1, ox1), uy = fminf(sy1, oy1);
    float xr = 14.f / fmaxf(sx2 - ux, ox2 - ux);
    float yr = 14.f / fmaxf(sy2 - uy, oy2 - uy);
    float xs0 = rintf((sx1 - ux) * xr), xs1 = rintf((sx2 - ux) * xr);
    float xo0 = rintf((ox1 - ux) * xr), xo1 = rintf((ox2 - ux) * xr);
    float ys0 = rintf((sy1 - uy) * yr), ys1 = rintf((sy2 - uy) * yr);
    float yo0 = rintf((oy1 - uy) * yr), yo1 = rintf((oy2 - uy) * yr);
    int a = t / 14, b = t - a * 14;
    float fa = (float)a, fb = (float)b;
    float sm = (fa >= xs0 && fa < xs1 && fb >= ys0 && fb < ys1) ? 1.f : 0.f;
    float om = (fa >= xo0 && fa < xo1 && fb >= yo0 && fb < yo1) ? 1.f : 0.f;
    float bm = fminf(fmaxf(1.f - sm - om, 0.f), 1.f);
    wS[t] = sm; wO[t] = om; wB[t] = bm;
  }
  __syncthreads();
  const float4* u4 = (const float4*)(uf + ((size_t)p * DD + t) * SP);
  float as0 = 0, as1 = 0, ao0 = 0, ao1 = 0, ab0 = 0, ab1 = 0;
#pragma unroll 7
  for (int j = 0; j < SP / 4; ++j) {
    float4 v  = u4[j];
    float4 ms = *(const float4*)&wS[4 * j];
    float4 mo = *(const float4*)&wO[4 * j];
    float4 mb = *(const float4*)&wB[4 * j];
    as0 += v.x * ms.x + v.y * ms.y;  as1 += v.z * ms.z + v.w * ms.w;
    ao0 += v.x * mo.x + v.y * mo.y;  ao1 += v.z * mo.z + v.w * mo.w;
    ab0 += v.x * mb.x + v.y * mb.y;  ab1 += v.z * mb.z + v.w * mb.w;
  }
  const float inv = 1.f / 196.f;
  float* o = sAll + (size_t)p * 768;
  o[t]       = (as0 + as1) * inv;
  o[256 + t] = (ao0 + ao1) * inv;
  o[512 + t] = (ab0 + ab1) * inv;
}

// ============ K4: fused attention gates + rel MLP (4 pairs / block) ========
__global__ void k_attrel(const float* __restrict__ sAll,
                         const float* __restrict__ f1wT, const float* __restrict__ f1b,
                         const float* __restrict__ f2wT, const float* __restrict__ f2b,
                         const float* __restrict__ Wc1T, const float* __restrict__ bc1,
                         const float* __restrict__ Wc2T, const float* __restrict__ bc2,
                         float* __restrict__ relf) {
  const int p0 = blockIdx.x * 4;
  const int t = threadIdx.x;
  __shared__ __align__(16) float sg[4][768];
  __shared__ __align__(16) float ha[4][192];
  __shared__ __align__(16) float h2[4][256];
  // stage 4 pair-rows (each 768) into LDS
  {
    const float4* src = (const float4*)(sAll + (size_t)p0 * 768);
    float4* dst = (float4*)&sg[0][0];
#pragma unroll
    for (int j = t; j < 768; j += 256) dst[j] = src[j];
  }
  __syncthreads();
  // phase 1: fc1 (3 branches x 64 cols), 4 pairs per thread
  if (t < 192) {
    const int br = t >> 6, c = t & 63;
    const float4* w4 = (const float4*)(f1wT + (br * 64 + c) * 256);
    const int sb = br * 256;
    float a0 = 0, a1 = 0, a2 = 0, a3 = 0;
#pragma unroll 8
    for (int j = 0; j < 64; ++j) {
      float4 wv = w4[j];
      float4 s0 = *(const float4*)&sg[0][sb + 4 * j];
      float4 s1 = *(const float4*)&sg[1][sb + 4 * j];
      float4 s2 = *(const float4*)&sg[2][sb + 4 * j];
      float4 s3 = *(const float4*)&sg[3][sb + 4 * j];
      a0 += s0.x * wv.x + s0.y * wv.y + s0.z * wv.z + s0.w * wv.w;
      a1 += s1.x * wv.x + s1.y * wv.y + s1.z * wv.z + s1.w * wv.w;
      a2 += s2.x * wv.x + s2.y * wv.y + s2.z * wv.z + s2.w * wv.w;
      a3 += s3.x * wv.x + s3.y * wv.y + s3.z * wv.z + s3.w * wv.w;
    }
    float bb = f1b[br * 64 + c];
    ha[0][t] = fmaxf(a0 + bb, 0.f);
    ha[1][t] = fmaxf(a1 + bb, 0.f);
    ha[2][t] = fmaxf(a2 + bb, 0.f);
    ha[3][t] = fmaxf(a3 + bb, 0.f);
  }
  __syncthreads();
  // phase 2: fc2 + sigmoid, gate sg in place
#pragma unroll
  for (int br = 0; br < 3; ++br) {
    const float4* w4 = (const float4*)(f2wT + br * 16384 + t * 64);
    const int hb = br * 64;
    float a0 = 0, a1 = 0, a2 = 0, a3 = 0;
#pragma unroll
    for (int j = 0; j < 16; ++j) {
      float4 wv = w4[j];
      float4 v0 = *(const float4*)&ha[0][hb + 4 * j];
      float4 v1 = *(const float4*)&ha[1][hb + 4 * j];
      float4 v2 = *(const float4*)&ha[2][hb + 4 * j];
      float4 v3 = *(const float4*)&ha[3][hb + 4 * j];
      a0 += v0.x * wv.x + v0.y * wv.y + v0.z * wv.z + v0.w * wv.w;
      a1 += v1.x * wv.x + v1.y * wv.y + v1.z * wv.z + v1.w * wv.w;
      a2 += v2.x * wv.x + v2.y * wv.y + v2.z * wv.z + v2.w * wv.w;
      a3 += v3.x * wv.x + v3.y * wv.y + v3.z * wv.z + v3.w * wv.w;
    }
    float bb = f2b[br * 256 + t];
    int ci = br * 256 + t;
    sg[0][ci] *= 1.f / (1.f + expf(-(a0 + bb)));
    sg[1][ci] *= 1.f / (1.f + expf(-(a1 + bb)));
    sg[2][ci] *= 1.f / (1.f + expf(-(a2 + bb)));
    sg[3][ci] *= 1.f / (1.f + expf(-(a3 + bb)));
  }
  __syncthreads();
  // phase 3: rel fc1 768->256, relu
  {
    const float4* w4 = (const float4*)(Wc1T + (size_t)t * 768);
    float a0 = 0, a1 = 0, a2 = 0, a3 = 0;
#pragma unroll 8
    for (int j = 0; j < 192; ++j) {
      float4 wv = w4[j];
      float4 g0 = *(const float4*)&sg[0][4 * j];
      float4 g1 = *(const float4*)&sg[1][4 * j];
      float4 g2 = *(const float4*)&sg[2][4 * j];
      float4 g3 = *(const float4*)&sg[3][4 * j];
      a0 += g0.x * wv.x + g0.y * wv.y + g0.z * wv.z + g0.w * wv.w;
      a1 += g1.x * wv.x + g1.y * wv.y + g1.z * wv.z + g1.w * wv.w;
      a2 += g2.x * wv.x + g2.y * wv.y + g2.z * wv.z + g2.w * wv.w;
      a3 += g3.x * wv.x + g3.y * wv.y + g3.z * wv.z + g3.w * wv.w;
    }
    float bb = bc1[t];
    h2[0][t] = fmaxf(a0 + bb, 0.f);
    h2[1][t] = fmaxf(a1 + bb, 0.f);
    h2[2][t] = fmaxf(a2 + bb, 0.f);
    h2[3][t] = fmaxf(a3 + bb, 0.f);
  }
  __syncthreads();
  // phase 4: rel fc2 256->256
  {
    const float4* w4 = (const float4*)(Wc2T + (size_t)t * 256);
    float a0 = 0, a1 = 0, a2 = 0, a3 = 0;
#pragma unroll 8
    for (int j = 0; j < 64; ++j) {
      float4 wv = w4[j];
      float4 v0 = *(const float4*)&h2[0][4 * j];
      float4 v1 = *(const float4*)&h2[1][4 * j];
      float4 v2 = *(const float4*)&h2[2][4 * j];
      float4 v3 = *(const float4*)&h2[3][4 * j];
      a0 += v0.x * wv.x + v0.y * wv.y + v0.z * wv.z + v0.w * wv.w;
      a1 += v1.x * wv.x + v1.y * wv.y + v1.z * wv.z + v1.w * wv.w;
      a2 += v2.x * wv.x + v2.y * wv.y + v2.z * wv.z + v2.w * wv.w;
      a3 += v3.x * wv.x + v3.y * wv.y + v3.z * wv.z + v3.w * wv.w;
    }
    float bb = bc2[t];
    relf[(size_t)(p0 + 0) * DD + t] = a0 + bb;
    relf[(size_t)(p0 + 1) * DD + t] = a1 + bb;
    relf[(size_t)(p0 + 2) * DD + t] = a2 + bb;
    relf[(size_t)(p0 + 3) * DD + t] = a3 + bb;
  }
}

// ============ K5: H = concat(objf, relf) @ Wg (2 rows / block) =============
__global__ void k_gcn_h(const float* __restrict__ objf, const float* __restrict__ relf,
                        const float* __restrict__ WgT, float* __restrict__ H) {
  const int r0 = blockIdx.x * 2;
  const int t = threadIdx.x;
  __shared__ __align__(16) float fin[2][DD];
#pragma unroll
  for (int r = 0; r < 2; ++r) {
    int row = r0 + r;
    fin[r][t] = (row < NOBJ) ? objf[row * DD + t]
                             : relf[(size_t)(row - NOBJ) * DD + t];
  }
  __syncthreads();
  const float4* w4 = (const float4*)(WgT + (size_t)t * DD);
  float a0 = 0, a1 = 0;
#pragma unroll 8
  for (int j = 0; j < DD / 4; ++j) {
    float4 wv = w4[j];
    float4 f0 = *(const float4*)&fin[0][4 * j];
    float4 f1 = *(const float4*)&fin[1][4 * j];
    a0 += f0.x * wv.x + f0.y * wv.y + f0.z * wv.z + f0.w * wv.w;
    a1 += f1.x * wv.x + f1.y * wv.y + f1.z * wv.z + f1.w * wv.w;
  }
  H[(size_t)(r0 + 0) * DD + t] = a0;
  H[(size_t)(r0 + 1) * DD + t] = a1;
}

// ============ K6: object GCN rows + obj head (1024 threads) ================
__global__ void k_obj_out(const float* __restrict__ H, const float* __restrict__ objf,
                          const int* __restrict__ pairs, const float* __restrict__ bg,
                          const float* __restrict__ WopT, const float* __restrict__ bop,
                          float* __restrict__ out) {
  const int i = blockIdx.x, t = threadIdx.x;
  const int slice = t >> 8, tt = t & 255;
  __shared__ int2 pr[NP];
  __shared__ float red[4][DD];
  __shared__ __align__(16) float gr[DD];
  const int2* p2 = (const int2*)pairs;
  for (int r = t; r < NP; r += 1024) pr[r] = p2[r];
  __syncthreads();
  float acc = 0.f;
  if (slice == 0) {
#pragma unroll 8
    for (int j = 0; j < NOBJ; ++j) acc += H[j * DD + tt];
  }
  const int rbeg = slice * 248;
#pragma unroll 8
  for (int r = rbeg; r < rbeg + 248; ++r) {
    int2 q = pr[r];
    float v = H[(size_t)(NOBJ + r) * DD + tt];
    if (q.x == i || q.y == i) acc += v;
  }
  red[slice][tt] = acc;
  __syncthreads();
  if (t < DD) {
    float pre = (red[0][t] + red[1][t] + red[2][t] + red[3][t]) * (1.f / 94.f);
    gr[t] = fmaxf(pre + bg[t], 0.f) + objf[i * DD + t];
  }
  __syncthreads();
  float hsum = 0.f;
  if (tt < OC) {
    const float4* w4 = (const float4*)(WopT + tt * 256 + slice * 64);
#pragma unroll
    for (int j = 0; j < 16; ++j) {
      float4 wv = w4[j];
      float4 gv = *(const float4*)&gr[slice * 64 + 4 * j];
      hsum += gv.x * wv.x + gv.y * wv.y + gv.z * wv.z + gv.w * wv.w;
    }
  }
  red[slice][tt] = hsum;
  __syncthreads();
  if (t < OC)
    out[i * OC + t] = red[0][t] + red[1][t] + red[2][t] + red[3][t] + bop[t];
}

// ============ K7: rel GCN rows + rel head ==================================
__global__ void k_rel_out(const float* __restrict__ H, const float* __restrict__ relf,
                          const int* __restrict__ pairs, const float* __restrict__ bg,
                          const float* __restrict__ WrpT, const float* __restrict__ brp,
                          float* __restrict__ out) {
  const int r = blockIdx.x, t = threadIdx.x;
  __shared__ __align__(16) float gr[DD];
  __shared__ float red[4][64];
  int si = pairs[2 * r], oi = pairs[2 * r + 1];
  float hsum = H[si * DD + t] + H[oi * DD + t] + H[(size_t)(NOBJ + r) * DD + t];
  gr[t] = fmaxf(hsum * (1.f / 3.f) + bg[t], 0.f) + relf[(size_t)r * DD + t];
  __syncthreads();
  const int q = t >> 6, c = t & 63;
  float a = 0.f;
  if (c < RC) {
    const float4* w4 = (const float4*)(WrpT + c * 256 + q * 64);
#pragma unroll
    for (int j = 0; j < 16; ++j) {
      float4 wv = w4[j];
      float4 gv = *(const float4*)&gr[q * 64 + 4 * j];
      a += gv.x * wv.x + gv.y * wv.y + gv.z * wv.z + gv.w * wv.w;
    }
  }
  red[q][c] = a;
  __syncthreads();
  if (t < RC)
    out[NOBJ * OC + (size_t)r * RC + t] =
        red[0][t] + red[1][t] + red[2][t] + red[3][t] + brp[t];
}

extern "C" void kernel_launch(void* const* d_in, const int* in_sizes, int n_in,
                              void* d_out, int out_size, void* d_ws, size_t ws_size,
                              hipStream_t stream) {
  const float* roi   = (const float*)d_in[0];
  const float* bbox  = (const float*)d_in[1];
  const float* logit = (const float*)d_in[2];
  const float* uf    = (const float*)d_in[3];
  const int*   pairs = (const int*)d_in[4];
  const float* W1    = (const float*)d_in[5];
  const float* b1    = (const float*)d_in[6];
  const float* W2    = (const float*)d_in[7];
  const float* b2    = (const float*)d_in[8];
  const float* fc1w  = (const float*)d_in[9];
  const float* fc1b  = (const float*)d_in[10];
  const float* fc2w  = (const float*)d_in[11];
  const float* fc2b  = (const float*)d_in[12];
  const float* Wc1   = (const float*)d_in[13];
  const float* bc1   = (const float*)d_in[14];
  const float* Wc2   = (const float*)d_in[15];
  const float* bc2   = (const float*)d_in[16];
  const float* Wg    = (const float*)d_in[17];
  const float* bg    = (const float*)d_in[18];
  const float* Wop   = (const float*)d_in[19];
  const float* bop   = (const float*)d_in[20];
  const float* Wrp   = (const float*)d_in[21];
  const float* brp   = (const float*)d_in[22];

  float* ws    = (float*)d_ws;
  float* part  = ws + OFF_PART;
  float* objf  = ws + OFF_OBJF;
  float* sAll  = ws + OFF_SALL;
  float* relf  = ws + OFF_RELF;
  float* Hbuf  = ws + OFF_H;
  float* W2T   = ws + OFF_W2T;
  float* Wc1T  = ws + OFF_WC1T;
  float* Wc2T  = ws + OFF_WC2T;
  float* WgT   = ws + OFF_WGT;
  float* f1wT  = ws + OFF_FC1WT;
  float* f2wT  = ws + OFF_FC2WT;
  float* WopT  = ws + OFF_WOPT;
  float* WrpT  = ws + OFF_WRPT;
  float* out   = (float*)d_out;

  k_transpose<<<2122, 256, 0, stream>>>(W2, Wc1, Wc2, Wg, fc1w, fc2w, Wop, Wrp,
                                        W2T, Wc1T, Wc2T, WgT, f1wT, f2wT, WopT, WrpT);
  k_emb1_partial<<<CH, 256, 0, stream>>>(roi, logit, bbox, W1, part);
  k_union<<<NP, 256, 0, stream>>>(uf, bbox, pairs, sAll);
  k_emb2<<<NOBJ, 256, 0, stream>>>(part, b1, W2T, b2, objf);
  k_attrel<<<NP / 4, 256, 0, stream>>>(sAll, f1wT, fc1b, f2wT, fc2b,
                                       Wc1T, bc1, Wc2T, bc2, relf);
  k_gcn_h<<<(NOBJ + NP) / 2, 256, 0, stream>>>(objf, relf, WgT, Hbuf);
  k_obj_out<<<NOBJ, 1024, 0, stream>>>(Hbuf, objf, pairs, bg, WopT, bop, out);
  k_rel_out<<<NP, 256, 0, stream>>>(Hbuf, relf, pairs, bg, WrpT, brp, out);
}